// Round 5
// baseline (17865.996 us; speedup 1.0000x reference)
//
#include <hip/hip_runtime.h>
#include <hip/hip_bf16.h>

// Problem constants: N=100000, F=128, O=128, S=4, B=2, E=3200000
#define NN 100000
#define FF 128
#define OO 128
#define SS 4
#define BBASES 2
#define EE 3200000
#define TOTE (SS * EE)               // 12.8M edges total
#define RR 32                        // dest rows per bin
#define RSHIFT 5
#define NBINS ((NN + RR - 1) / RR)   // 3125
#define RBLOCKS 512                  // blocks for hist/reorder

// clang vector types usable with __builtin_nontemporal_* (HIP uint2/float4 are not)
typedef unsigned int uintx2 __attribute__((ext_vector_type(2)));
typedef float floatx4 __attribute__((ext_vector_type(4)));

// ===========================================================================
// out[n] = tanh( G0[n] @ W0 + G1[n] @ W1 ),
// G_b[n] = sum_s Wc[s,b] * sum_{e in support s: row_e=n} val_e * feat[col_e]
// Edges binned by dest row (32/bin); block per bin accumulates G0,G1 in LDS,
// then 32x128x(2x128) GEMM + tanh. Accumulate phase: 16 edges per wave-iter
// in one basic block -> 16 independent 512B gathers in flight per wave.
// ===========================================================================

__global__ __launch_bounds__(256) void hist_kernel(const int* __restrict__ rows,
                                                   unsigned int* __restrict__ hist) {
  __shared__ unsigned int lh[NBINS];
  for (int i = threadIdx.x; i < NBINS; i += 256) lh[i] = 0;
  __syncthreads();
  const int stride = gridDim.x * 256;
  for (int i = blockIdx.x * 256 + threadIdx.x; i < TOTE; i += stride)
    atomicAdd(&lh[((unsigned)rows[i]) >> RSHIFT], 1u);
  __syncthreads();
  for (int i = threadIdx.x; i < NBINS; i += 256) {
    unsigned int c = lh[i];
    if (c) atomicAdd(&hist[i], c);
  }
}

__global__ __launch_bounds__(256) void scan_kernel(const unsigned int* __restrict__ hist,
                                                   unsigned int* __restrict__ bin_start,
                                                   unsigned int* __restrict__ cursor) {
  __shared__ unsigned int sums[256];
  const int C = (NBINS + 255) / 256;  // 13
  const int t = threadIdx.x;
  unsigned int s = 0;
  for (int j = 0; j < C; ++j) {
    int i = t * C + j;
    if (i < NBINS) s += hist[i];
  }
  sums[t] = s;
  __syncthreads();
  for (int off = 1; off < 256; off <<= 1) {
    unsigned int v = (t >= off) ? sums[t - off] : 0u;
    __syncthreads();
    sums[t] += v;
    __syncthreads();
  }
  unsigned int base = (t == 0) ? 0u : sums[t - 1];
  for (int j = 0; j < C; ++j) {
    int i = t * C + j;
    if (i < NBINS) {
      unsigned int h = hist[i];
      bin_start[i] = base;
      cursor[i] = base;
      base += h;
    }
  }
  if (t == 255) bin_start[NBINS] = base;  // == TOTE
}

__global__ __launch_bounds__(256) void reorder_kernel(
    const int* __restrict__ rows, const int* __restrict__ cols,
    const float* __restrict__ vals, unsigned int* __restrict__ cursor,
    uintx2* __restrict__ sorted) {
  __shared__ unsigned int lcnt[NBINS];
  __shared__ unsigned int lbase[NBINS];
  const int C = (TOTE + RBLOCKS - 1) / RBLOCKS;  // 25000
  const int start = blockIdx.x * C;
  const int end = min(start + C, TOTE);
  for (int i = threadIdx.x; i < NBINS; i += 256) lcnt[i] = 0;
  __syncthreads();
  for (int i = start + threadIdx.x; i < end; i += 256)
    atomicAdd(&lcnt[((unsigned)rows[i]) >> RSHIFT], 1u);
  __syncthreads();
  for (int i = threadIdx.x; i < NBINS; i += 256) {
    unsigned int c = lcnt[i];
    if (c) lbase[i] = atomicAdd(&cursor[i], c);
    lcnt[i] = 0;
  }
  __syncthreads();
  for (int i = start + threadIdx.x; i < end; i += 256) {
    unsigned int r = (unsigned)rows[i];
    int bin = r >> RSHIFT;
    unsigned int p = lbase[bin] + atomicAdd(&lcnt[bin], 1u);
    int s = i / EE;  // support id
    uintx2 rec;
    rec.x = ((unsigned)cols[i]) | ((r & (RR - 1u)) << 17) | (((unsigned)s) << 22);
    rec.y = __float_as_uint(vals[i]);
    __builtin_nontemporal_store(rec, &sorted[p]);
  }
}

// ---- fused: 16-edge-batched LDS accumulate + GEMM + tanh ------------------
// G LDS layout is de-interleaved: feature element 2l -> slot l, 2l+1 -> 64+l.
__global__ __launch_bounds__(256, 4) void fused_kernel(
    const float* __restrict__ feat, const float* __restrict__ W,
    const float* __restrict__ Wc, const uintx2* __restrict__ sorted,
    const unsigned int* __restrict__ bin_start, float* __restrict__ out) {
  __shared__ float G[2 * RR * FF];  // 32 KB
  const int tid = threadIdx.x;

  float4* gz = (float4*)G;
#pragma unroll
  for (int i = 0; i < (2 * RR * FF / 4) / 256; ++i)  // 8 iters
    gz[tid + i * 256] = make_float4(0.f, 0.f, 0.f, 0.f);

  const float c00 = Wc[0], c01 = Wc[1], c10 = Wc[2], c11 = Wc[3];
  const float c20 = Wc[4], c21 = Wc[5], c30 = Wc[6], c31 = Wc[7];
  __syncthreads();

  const int bin = blockIdx.x;
  const unsigned int e0 = bin_start[bin];
  const unsigned int e1 = bin_start[bin + 1];
  const int lane = tid & 63;
  const int wid = tid >> 6;  // 0..3

  unsigned int base = e0 + (wid << 4);
  for (; base + 16 <= e1; base += 64) {
    // 1) 16 edge records (uniform 8B loads, nontemporal)
    uintx2 cv[16];
#pragma unroll
    for (int j = 0; j < 16; ++j)
      cv[j] = __builtin_nontemporal_load(&sorted[base + j]);
    // 2) 16 independent 512B gathers (one dwordx2 per lane per edge)
    float2 x[16];
#pragma unroll
    for (int j = 0; j < 16; ++j) {
      int col = cv[j].x & 0x1FFFF;
      x[j] = *reinterpret_cast<const float2*>(&feat[(col << 7) + (lane << 1)]);
    }
    // 3) decode + 4 ds_add per edge (stride-1 across lanes: conflict-free)
#pragma unroll
    for (int j = 0; j < 16; ++j) {
      float v = __uint_as_float(cv[j].y);
      int s = cv[j].x >> 22;
      int ro = (cv[j].x >> 17) & (RR - 1);
      float w0 = (s == 0) ? c00 : (s == 1) ? c10 : (s == 2) ? c20 : c30;
      float w1 = (s == 0) ? c01 : (s == 1) ? c11 : (s == 2) ? c21 : c31;
      float v0 = v * w0, v1 = v * w1;
      int a = (ro << 7) + lane;
      atomicAdd(&G[a], v0 * x[j].x);
      atomicAdd(&G[a + 64], v0 * x[j].y);
      atomicAdd(&G[RR * FF + a], v1 * x[j].x);
      atomicAdd(&G[RR * FF + a + 64], v1 * x[j].y);
    }
  }
  // tail: < 16 edges for this wave
  if (base < e1) {
    unsigned int stop = (base + 16 < e1) ? base + 16 : e1;
    for (unsigned int e = base; e < stop; ++e) {
      uintx2 cv = sorted[e];
      float v = __uint_as_float(cv.y);
      int col = cv.x & 0x1FFFF;
      int ro = (cv.x >> 17) & (RR - 1);
      int s = cv.x >> 22;
      float w0 = (s == 0) ? c00 : (s == 1) ? c10 : (s == 2) ? c20 : c30;
      float w1 = (s == 0) ? c01 : (s == 1) ? c11 : (s == 2) ? c21 : c31;
      float2 xx = *reinterpret_cast<const float2*>(&feat[(col << 7) + (lane << 1)]);
      float v0 = v * w0, v1 = v * w1;
      int a = (ro << 7) + lane;
      atomicAdd(&G[a], v0 * xx.x);
      atomicAdd(&G[a + 64], v0 * xx.y);
      atomicAdd(&G[RR * FF + a], v1 * xx.x);
      atomicAdd(&G[RR * FF + a + 64], v1 * xx.y);
    }
  }
  __syncthreads();

  // GEMM epilogue with de-interleave remap: element k=2h+p lives at slot p*64+h
  const int tx = tid & 31;   // output cols tx*4 .. tx*4+3
  const int ty = tid >> 5;   // 0..7 -> rows ty*4 .. ty*4+3
  float acc[4][4];
#pragma unroll
  for (int r = 0; r < 4; ++r)
#pragma unroll
    for (int c = 0; c < 4; ++c) acc[r][c] = 0.f;

  const float* W0 = W;
  const float* W1 = W + FF * OO;
#pragma unroll
  for (int p = 0; p < 2; ++p) {
    for (int h = 0; h < 64; ++h) {
      int k = 2 * h + p;
      float4 b0 = *(const float4*)&W0[k * OO + tx * 4];
      float4 b1 = *(const float4*)&W1[k * OO + tx * 4];
      int slot = p * 64 + h;
#pragma unroll
      for (int r = 0; r < 4; ++r) {
        float a0 = G[((ty * 4 + r) << 7) + slot];
        float a1 = G[RR * FF + ((ty * 4 + r) << 7) + slot];
        acc[r][0] += a0 * b0.x + a1 * b1.x;
        acc[r][1] += a0 * b0.y + a1 * b1.y;
        acc[r][2] += a0 * b0.z + a1 * b1.z;
        acc[r][3] += a0 * b0.w + a1 * b1.w;
      }
    }
  }
#pragma unroll
  for (int r = 0; r < 4; ++r) {
    int row = bin * RR + ty * 4 + r;  // N divisible by RR
    floatx4 o;
    o.x = tanhf(acc[r][0]);
    o.y = tanhf(acc[r][1]);
    o.z = tanhf(acc[r][2]);
    o.w = tanhf(acc[r][3]);
    __builtin_nontemporal_store(o, (floatx4*)&out[(size_t)row * OO + tx * 4]);
  }
}

// ===========================================================================
// FALLBACK PATH (round-1, proven): used only if ws_size is too small
// ===========================================================================
__global__ void compute_V_kernel(const float* __restrict__ W,
                                 const float* __restrict__ Wc,
                                 float* __restrict__ V) {
  int i = blockIdx.x * blockDim.x + threadIdx.x;
  int s = i >> 14;
  int fo = i & 16383;
  V[i] = Wc[s * BBASES + 0] * W[fo] + Wc[s * BBASES + 1] * W[16384 + fo];
}

__global__ __launch_bounds__(256) void scatter_kernel(
    const float* __restrict__ feat, const int* __restrict__ rows,
    const int* __restrict__ cols, const float* __restrict__ vals,
    float* __restrict__ agg) {
  int t = blockIdx.x * blockDim.x + threadIdx.x;
  int e = t >> 5;
  int q = t & 31;
  if (e >= EE) return;
  int r = rows[e];
  int c = cols[e];
  float v = vals[e];
  const float4 x = *reinterpret_cast<const float4*>(&feat[(size_t)c * FF + q * 4]);
  float* dst = &agg[(size_t)r * FF + q * 4];
  unsafeAtomicAdd(dst + 0, v * x.x);
  unsafeAtomicAdd(dst + 1, v * x.y);
  unsafeAtomicAdd(dst + 2, v * x.z);
  unsafeAtomicAdd(dst + 3, v * x.w);
}

__global__ __launch_bounds__(256) void gemm_acc_kernel(
    const float* __restrict__ A, const float* __restrict__ Bv,
    float* __restrict__ C) {
  __shared__ float As[16][64];
  __shared__ float Bs[16][128];
  const int tid = threadIdx.x;
  const int bm0 = blockIdx.x * 64;
  const int tx = tid & 31;
  const int ty = tid >> 5;
  float acc[8][4];
#pragma unroll
  for (int r = 0; r < 8; ++r)
#pragma unroll
    for (int c = 0; c < 4; ++c) acc[r][c] = 0.0f;
  const int ar = tid >> 2;
  const int akq = tid & 3;
  for (int k0 = 0; k0 < FF; k0 += 16) {
    {
      int row = bm0 + ar;
      float4 av = make_float4(0.f, 0.f, 0.f, 0.f);
      if (row < NN)
        av = *reinterpret_cast<const float4*>(&A[(size_t)row * FF + k0 + akq * 4]);
      As[akq * 4 + 0][ar] = av.x;
      As[akq * 4 + 1][ar] = av.y;
      As[akq * 4 + 2][ar] = av.z;
      As[akq * 4 + 3][ar] = av.w;
    }
#pragma unroll
    for (int i = 0; i < 2; ++i) {
      int v = tid + i * 256;
      int kk = v >> 5;
      int cq = v & 31;
      *reinterpret_cast<float4*>(&Bs[kk][cq * 4]) =
          *reinterpret_cast<const float4*>(&Bv[(k0 + kk) * OO + cq * 4]);
    }
    __syncthreads();
#pragma unroll
    for (int kk = 0; kk < 16; ++kk) {
      float4 b = *reinterpret_cast<const float4*>(&Bs[kk][tx * 4]);
#pragma unroll
      for (int r = 0; r < 8; ++r) {
        float a = As[kk][ty * 8 + r];
        acc[r][0] += a * b.x;
        acc[r][1] += a * b.y;
        acc[r][2] += a * b.z;
        acc[r][3] += a * b.w;
      }
    }
    __syncthreads();
  }
#pragma unroll
  for (int r = 0; r < 8; ++r) {
    int row = bm0 + ty * 8 + r;
    if (row < NN) {
      float4* cp = reinterpret_cast<float4*>(&C[(size_t)row * OO + tx * 4]);
      float4 c = *cp;
      c.x += acc[r][0];
      c.y += acc[r][1];
      c.z += acc[r][2];
      c.w += acc[r][3];
      *cp = c;
    }
  }
}

__global__ __launch_bounds__(256) void tanh_kernel(float* __restrict__ out) {
  int i = blockIdx.x * blockDim.x + threadIdx.x;
  float4* p = reinterpret_cast<float4*>(out) + i;
  float4 v = *p;
  v.x = tanhf(v.x);
  v.y = tanhf(v.y);
  v.z = tanhf(v.z);
  v.w = tanhf(v.w);
  *p = v;
}

// ===========================================================================
extern "C" void kernel_launch(void* const* d_in, const int* in_sizes, int n_in,
                              void* d_out, int out_size, void* d_ws,
                              size_t ws_size, hipStream_t stream) {
  const float* feat = (const float*)d_in[0];   // [N, F]
  const float* W = (const float*)d_in[1];      // [B, F, O]
  const float* Wc = (const float*)d_in[2];     // [S, B]
  const int* erows = (const int*)d_in[3];      // [S, E]
  const int* ecols = (const int*)d_in[4];      // [S, E]
  const float* evals = (const float*)d_in[5];  // [S, E]
  float* out = (float*)d_out;                  // [N, O] f32

  unsigned char* ws = (unsigned char*)d_ws;
  unsigned int* hist = (unsigned int*)ws;                 // NBINS
  unsigned int* bin_start = hist + NBINS;                 // NBINS+1
  unsigned int* cursor = bin_start + NBINS + 1;           // NBINS
  size_t sorted_off = (((size_t)(3 * NBINS + 1) * 4) + 255) & ~(size_t)255;
  uintx2* sorted = (uintx2*)(ws + sorted_off);            // TOTE * 8B
  size_t needed = sorted_off + (size_t)TOTE * 8;

  if (ws_size >= needed) {
    hipMemsetAsync(hist, 0, (size_t)NBINS * 4, stream);
    hist_kernel<<<RBLOCKS, 256, 0, stream>>>(erows, hist);
    scan_kernel<<<1, 256, 0, stream>>>(hist, bin_start, cursor);
    reorder_kernel<<<RBLOCKS, 256, 0, stream>>>(erows, ecols, evals, cursor, sorted);
    fused_kernel<<<NBINS, 256, 0, stream>>>(feat, W, Wc, sorted, bin_start, out);
  } else {
    float* V = (float*)d_ws;
    float* agg = V + (size_t)SS * FF * OO;
    compute_V_kernel<<<(SS * FF * OO) / 256, 256, 0, stream>>>(W, Wc, V);
    hipMemsetAsync(out, 0, (size_t)NN * OO * sizeof(float), stream);
    for (int s = 0; s < SS; ++s) {
      hipMemsetAsync(agg, 0, (size_t)NN * FF * sizeof(float), stream);
      scatter_kernel<<<(EE * 32) / 256, 256, 0, stream>>>(
          feat, erows + (size_t)s * EE, ecols + (size_t)s * EE,
          evals + (size_t)s * EE, agg);
      gemm_acc_kernel<<<(NN + 63) / 64, 256, 0, stream>>>(
          agg, V + (size_t)s * FF * OO, out);
    }
    tanh_kernel<<<(NN * OO / 4) / 256, 256, 0, stream>>>(out);
  }
}

// Round 6
// 8990.914 us; speedup vs baseline: 1.9871x; 1.9871x over previous
//
#include <hip/hip_runtime.h>
#include <hip/hip_bf16.h>

// Problem constants: N=100000, F=128, O=128, S=4, B=2, E=3200000
#define NN 100000
#define FF 128
#define OO 128
#define SS 4
#define BBASES 2
#define EE 3200000
#define TOTE (SS * EE)               // 12.8M edges total
#define RR 16                        // dest rows per bin
#define RSHIFT 4
#define NBINS ((NN + RR - 1) / RR)   // 6250
#define RBLOCKS 512                  // blocks for hist/reorder

// clang vector types usable with __builtin_nontemporal_* (HIP uint2/float4 are not)
typedef unsigned int uintx2 __attribute__((ext_vector_type(2)));
typedef float floatx4 __attribute__((ext_vector_type(4)));

// ===========================================================================
// out[n] = tanh( sum_b (sum_s Wc[s,b] * A_s X)[n] @ W_b )
// Stage 1: bin all 12.8M edges by dest row (16 rows/bin).
// Stage 2 (fused): per bin, accumulate per-support G_s[16][128] in LDS.
//   Edge records arrive 64-per-wave in ONE coalesced load; readlane
//   broadcasts break the record->gather dependency so 16 gathers stay in
//   flight per wave. 2 LDS atomics per edge. Then epilogue folds supports
//   with Wc, does the 16x128x(2x128) GEMM + tanh, one store per output.
// ===========================================================================

__global__ __launch_bounds__(256) void hist_kernel(const int* __restrict__ rows,
                                                   unsigned int* __restrict__ hist) {
  __shared__ unsigned int lh[NBINS];
  for (int i = threadIdx.x; i < NBINS; i += 256) lh[i] = 0;
  __syncthreads();
  const int stride = gridDim.x * 256;
  for (int i = blockIdx.x * 256 + threadIdx.x; i < TOTE; i += stride)
    atomicAdd(&lh[((unsigned)rows[i]) >> RSHIFT], 1u);
  __syncthreads();
  for (int i = threadIdx.x; i < NBINS; i += 256) {
    unsigned int c = lh[i];
    if (c) atomicAdd(&hist[i], c);
  }
}

__global__ __launch_bounds__(256) void scan_kernel(const unsigned int* __restrict__ hist,
                                                   unsigned int* __restrict__ bin_start,
                                                   unsigned int* __restrict__ cursor) {
  __shared__ unsigned int sums[256];
  const int C = (NBINS + 255) / 256;  // 25
  const int t = threadIdx.x;
  unsigned int s = 0;
  for (int j = 0; j < C; ++j) {
    int i = t * C + j;
    if (i < NBINS) s += hist[i];
  }
  sums[t] = s;
  __syncthreads();
  for (int off = 1; off < 256; off <<= 1) {
    unsigned int v = (t >= off) ? sums[t - off] : 0u;
    __syncthreads();
    sums[t] += v;
    __syncthreads();
  }
  unsigned int base = (t == 0) ? 0u : sums[t - 1];
  for (int j = 0; j < C; ++j) {
    int i = t * C + j;
    if (i < NBINS) {
      unsigned int h = hist[i];
      bin_start[i] = base;
      cursor[i] = base;
      base += h;
    }
  }
  if (t == 255) bin_start[NBINS] = base;  // == TOTE
}

__global__ __launch_bounds__(256) void reorder_kernel(
    const int* __restrict__ rows, const int* __restrict__ cols,
    const float* __restrict__ vals, unsigned int* __restrict__ cursor,
    uintx2* __restrict__ sorted) {
  __shared__ unsigned int lcnt[NBINS];
  __shared__ unsigned int lbase[NBINS];
  const int C = (TOTE + RBLOCKS - 1) / RBLOCKS;  // 25000
  const int start = blockIdx.x * C;
  const int end = min(start + C, TOTE);
  for (int i = threadIdx.x; i < NBINS; i += 256) lcnt[i] = 0;
  __syncthreads();
  for (int i = start + threadIdx.x; i < end; i += 256)
    atomicAdd(&lcnt[((unsigned)rows[i]) >> RSHIFT], 1u);
  __syncthreads();
  for (int i = threadIdx.x; i < NBINS; i += 256) {
    unsigned int c = lcnt[i];
    if (c) lbase[i] = atomicAdd(&cursor[i], c);
    lcnt[i] = 0;
  }
  __syncthreads();
  for (int i = start + threadIdx.x; i < end; i += 256) {
    unsigned int r = (unsigned)rows[i];
    int bin = r >> RSHIFT;
    unsigned int p = lbase[bin] + atomicAdd(&lcnt[bin], 1u);
    int s = i / EE;  // support id
    uintx2 rec;
    // bits [16:0]=col, [20:17]=row-in-bin, [22:21]=support
    rec.x = ((unsigned)cols[i]) | ((r & (RR - 1u)) << 17) | (((unsigned)s) << 21);
    rec.y = __float_as_uint(vals[i]);
    __builtin_nontemporal_store(rec, &sorted[p]);
  }
}

// ---- fused: wave-batched LDS accumulate + support-fold GEMM + tanh --------
// G_s LDS layout de-interleaved: feature element 2l -> slot l, 2l+1 -> 64+l.
__global__ __launch_bounds__(256, 4) void fused_kernel(
    const float* __restrict__ feat, const float* __restrict__ W,
    const float* __restrict__ Wc, const uintx2* __restrict__ sorted,
    const unsigned int* __restrict__ bin_start, float* __restrict__ out) {
  __shared__ float G[SS * RR * FF];  // 4 * 16 * 128 * 4B = 32 KB
  const int tid = threadIdx.x;

  float4* gz = (float4*)G;
#pragma unroll
  for (int i = 0; i < (SS * RR * FF / 4) / 256; ++i)  // 8 iters
    gz[tid + i * 256] = make_float4(0.f, 0.f, 0.f, 0.f);

  const float c00 = Wc[0], c01 = Wc[1], c10 = Wc[2], c11 = Wc[3];
  const float c20 = Wc[4], c21 = Wc[5], c30 = Wc[6], c31 = Wc[7];
  __syncthreads();

  const int bin = blockIdx.x;
  const unsigned int e0 = bin_start[bin];
  const unsigned int e1 = bin_start[bin + 1];
  const int lane = tid & 63;
  const int wid = tid >> 6;  // 0..3

  // ---- main: 64 edges per wave-iteration ----
  // Wave loads 64 records in ONE coalesced 512B load (double-buffered),
  // broadcasts fields via readlane (no memory latency), and issues gathers
  // in sub-batches of 16 with no intervening vmem waits.
  unsigned int base = e0 + ((unsigned)wid << 6);
  uintx2 cur;
  if (base + 64 <= e1) cur = sorted[base + lane];
  for (; base + 64 <= e1; base += 256) {
    const unsigned int nb = base + 256;
    uintx2 nxt;
    if (nb + 64 <= e1) nxt = sorted[nb + lane];
#pragma unroll
    for (int sb = 0; sb < 4; ++sb) {
      unsigned int rx[16];
      float2 x[16];
#pragma unroll
      for (int j = 0; j < 16; ++j) {
        rx[j] = (unsigned)__builtin_amdgcn_readlane((int)cur.x, sb * 16 + j);
        x[j] = *reinterpret_cast<const float2*>(
            &feat[((rx[j] & 0x1FFFFu) << 7) + (lane << 1)]);
      }
#pragma unroll
      for (int j = 0; j < 16; ++j) {
        float v = __uint_as_float(
            (unsigned)__builtin_amdgcn_readlane((int)cur.y, sb * 16 + j));
        unsigned int s = rx[j] >> 21;
        unsigned int ro = (rx[j] >> 17) & (RR - 1u);
        float* bs = &G[s * (RR * FF) + (ro << 7)];
        atomicAdd(bs + lane, v * x[j].x);
        atomicAdd(bs + 64 + lane, v * x[j].y);
      }
    }
    cur = nxt;
  }
  // ---- tail: < 64 edges remain; one edge per wave, serial (small) ----
  {
    unsigned int tstart = e0 + ((e1 - e0) & ~63u);
    for (unsigned int e = tstart + wid; e < e1; e += 4) {
      uintx2 cv = sorted[e];
      float v = __uint_as_float(cv.y);
      unsigned int col = cv.x & 0x1FFFFu;
      unsigned int ro = (cv.x >> 17) & (RR - 1u);
      unsigned int s = cv.x >> 21;
      float2 xx =
          *reinterpret_cast<const float2*>(&feat[(col << 7) + (lane << 1)]);
      float* bs = &G[s * (RR * FF) + (ro << 7)];
      atomicAdd(bs + lane, v * xx.x);
      atomicAdd(bs + 64 + lane, v * xx.y);
    }
  }
  __syncthreads();

  // ---- epilogue: fold supports with Wc, GEMM vs W0,W1, tanh, store ----
  // element k=2h+p lives at slot p*64+h of each G_s row.
  const int tx = tid & 31;  // output cols tx*4 .. tx*4+3
  const int ty = tid >> 5;  // 0..7 -> rows 2ty, 2ty+1
  float acc[2][4];
#pragma unroll
  for (int r = 0; r < 2; ++r)
#pragma unroll
    for (int c = 0; c < 4; ++c) acc[r][c] = 0.f;

  const float cb0[4] = {c00, c10, c20, c30};
  const float cb1[4] = {c01, c11, c21, c31};
  const float* W0 = W;
  const float* W1 = W + FF * OO;
#pragma unroll
  for (int p = 0; p < 2; ++p) {
    for (int h0 = 0; h0 < 64; h0 += 4) {
      float4 as_[2][4];
#pragma unroll
      for (int r = 0; r < 2; ++r)
#pragma unroll
        for (int s = 0; s < 4; ++s)
          as_[r][s] = *reinterpret_cast<const float4*>(
              &G[s * (RR * FF) + ((ty * 2 + r) << 7) + p * 64 + h0]);
#pragma unroll
      for (int i = 0; i < 4; ++i) {
        int k = 2 * (h0 + i) + p;
        float4 b0 = *reinterpret_cast<const float4*>(&W0[k * OO + tx * 4]);
        float4 b1 = *reinterpret_cast<const float4*>(&W1[k * OO + tx * 4]);
#pragma unroll
        for (int r = 0; r < 2; ++r) {
          float g0 = 0.f, g1 = 0.f;
#pragma unroll
          for (int s = 0; s < 4; ++s) {
            float a = reinterpret_cast<const float*>(&as_[r][s])[i];
            g0 += cb0[s] * a;
            g1 += cb1[s] * a;
          }
          acc[r][0] += g0 * b0.x + g1 * b1.x;
          acc[r][1] += g0 * b0.y + g1 * b1.y;
          acc[r][2] += g0 * b0.z + g1 * b1.z;
          acc[r][3] += g0 * b0.w + g1 * b1.w;
        }
      }
    }
  }
#pragma unroll
  for (int r = 0; r < 2; ++r) {
    int row = bin * RR + ty * 2 + r;  // N divisible by 16
    floatx4 o;
    o.x = tanhf(acc[r][0]);
    o.y = tanhf(acc[r][1]);
    o.z = tanhf(acc[r][2]);
    o.w = tanhf(acc[r][3]);
    __builtin_nontemporal_store(o, (floatx4*)&out[(size_t)row * OO + tx * 4]);
  }
}

// ===========================================================================
// FALLBACK PATH (round-1, proven): used only if ws_size is too small
// ===========================================================================
__global__ void compute_V_kernel(const float* __restrict__ W,
                                 const float* __restrict__ Wc,
                                 float* __restrict__ V) {
  int i = blockIdx.x * blockDim.x + threadIdx.x;
  int s = i >> 14;
  int fo = i & 16383;
  V[i] = Wc[s * BBASES + 0] * W[fo] + Wc[s * BBASES + 1] * W[16384 + fo];
}

__global__ __launch_bounds__(256) void scatter_kernel(
    const float* __restrict__ feat, const int* __restrict__ rows,
    const int* __restrict__ cols, const float* __restrict__ vals,
    float* __restrict__ agg) {
  int t = blockIdx.x * blockDim.x + threadIdx.x;
  int e = t >> 5;
  int q = t & 31;
  if (e >= EE) return;
  int r = rows[e];
  int c = cols[e];
  float v = vals[e];
  const float4 x = *reinterpret_cast<const float4*>(&feat[(size_t)c * FF + q * 4]);
  float* dst = &agg[(size_t)r * FF + q * 4];
  unsafeAtomicAdd(dst + 0, v * x.x);
  unsafeAtomicAdd(dst + 1, v * x.y);
  unsafeAtomicAdd(dst + 2, v * x.z);
  unsafeAtomicAdd(dst + 3, v * x.w);
}

__global__ __launch_bounds__(256) void gemm_acc_kernel(
    const float* __restrict__ A, const float* __restrict__ Bv,
    float* __restrict__ C) {
  __shared__ float As[16][64];
  __shared__ float Bs[16][128];
  const int tid = threadIdx.x;
  const int bm0 = blockIdx.x * 64;
  const int tx = tid & 31;
  const int ty = tid >> 5;
  float acc[8][4];
#pragma unroll
  for (int r = 0; r < 8; ++r)
#pragma unroll
    for (int c = 0; c < 4; ++c) acc[r][c] = 0.0f;
  const int ar = tid >> 2;
  const int akq = tid & 3;
  for (int k0 = 0; k0 < FF; k0 += 16) {
    {
      int row = bm0 + ar;
      float4 av = make_float4(0.f, 0.f, 0.f, 0.f);
      if (row < NN)
        av = *reinterpret_cast<const float4*>(&A[(size_t)row * FF + k0 + akq * 4]);
      As[akq * 4 + 0][ar] = av.x;
      As[akq * 4 + 1][ar] = av.y;
      As[akq * 4 + 2][ar] = av.z;
      As[akq * 4 + 3][ar] = av.w;
    }
#pragma unroll
    for (int i = 0; i < 2; ++i) {
      int v = tid + i * 256;
      int kk = v >> 5;
      int cq = v & 31;
      *reinterpret_cast<float4*>(&Bs[kk][cq * 4]) =
          *reinterpret_cast<const float4*>(&Bv[(k0 + kk) * OO + cq * 4]);
    }
    __syncthreads();
#pragma unroll
    for (int kk = 0; kk < 16; ++kk) {
      float4 b = *reinterpret_cast<const float4*>(&Bs[kk][tx * 4]);
#pragma unroll
      for (int r = 0; r < 8; ++r) {
        float a = As[kk][ty * 8 + r];
        acc[r][0] += a * b.x;
        acc[r][1] += a * b.y;
        acc[r][2] += a * b.z;
        acc[r][3] += a * b.w;
      }
    }
    __syncthreads();
  }
#pragma unroll
  for (int r = 0; r < 8; ++r) {
    int row = bm0 + ty * 8 + r;
    if (row < NN) {
      float4* cp = reinterpret_cast<float4*>(&C[(size_t)row * OO + tx * 4]);
      float4 c = *cp;
      c.x += acc[r][0];
      c.y += acc[r][1];
      c.z += acc[r][2];
      c.w += acc[r][3];
      *cp = c;
    }
  }
}

__global__ __launch_bounds__(256) void tanh_kernel(float* __restrict__ out) {
  int i = blockIdx.x * blockDim.x + threadIdx.x;
  float4* p = reinterpret_cast<float4*>(out) + i;
  float4 v = *p;
  v.x = tanhf(v.x);
  v.y = tanhf(v.y);
  v.z = tanhf(v.z);
  v.w = tanhf(v.w);
  *p = v;
}

// ===========================================================================
extern "C" void kernel_launch(void* const* d_in, const int* in_sizes, int n_in,
                              void* d_out, int out_size, void* d_ws,
                              size_t ws_size, hipStream_t stream) {
  const float* feat = (const float*)d_in[0];   // [N, F]
  const float* W = (const float*)d_in[1];      // [B, F, O]
  const float* Wc = (const float*)d_in[2];     // [S, B]
  const int* erows = (const int*)d_in[3];      // [S, E]
  const int* ecols = (const int*)d_in[4];      // [S, E]
  const float* evals = (const float*)d_in[5];  // [S, E]
  float* out = (float*)d_out;                  // [N, O] f32

  unsigned char* ws = (unsigned char*)d_ws;
  unsigned int* hist = (unsigned int*)ws;                 // NBINS
  unsigned int* bin_start = hist + NBINS;                 // NBINS+1
  unsigned int* cursor = bin_start + NBINS + 1;           // NBINS
  size_t sorted_off = (((size_t)(3 * NBINS + 1) * 4) + 255) & ~(size_t)255;
  uintx2* sorted = (uintx2*)(ws + sorted_off);            // TOTE * 8B
  size_t needed = sorted_off + (size_t)TOTE * 8;

  if (ws_size >= needed) {
    hipMemsetAsync(hist, 0, (size_t)NBINS * 4, stream);
    hist_kernel<<<RBLOCKS, 256, 0, stream>>>(erows, hist);
    scan_kernel<<<1, 256, 0, stream>>>(hist, bin_start, cursor);
    reorder_kernel<<<RBLOCKS, 256, 0, stream>>>(erows, ecols, evals, cursor, sorted);
    fused_kernel<<<NBINS, 256, 0, stream>>>(feat, W, Wc, sorted, bin_start, out);
  } else {
    float* V = (float*)d_ws;
    float* agg = V + (size_t)SS * FF * OO;
    compute_V_kernel<<<(SS * FF * OO) / 256, 256, 0, stream>>>(W, Wc, V);
    hipMemsetAsync(out, 0, (size_t)NN * OO * sizeof(float), stream);
    for (int s = 0; s < SS; ++s) {
      hipMemsetAsync(agg, 0, (size_t)NN * FF * sizeof(float), stream);
      scatter_kernel<<<(EE * 32) / 256, 256, 0, stream>>>(
          feat, erows + (size_t)s * EE, ecols + (size_t)s * EE,
          evals + (size_t)s * EE, agg);
      gemm_acc_kernel<<<(NN + 63) / 64, 256, 0, stream>>>(
          agg, V + (size_t)s * FF * OO, out);
    }
    tanh_kernel<<<(NN * OO / 4) / 256, 256, 0, stream>>>(out);
  }
}

// Round 7
// 4637.121 us; speedup vs baseline: 3.8528x; 1.9389x over previous
//
#include <hip/hip_runtime.h>
#include <hip/hip_bf16.h>

// Problem constants: N=100000, F=128, O=128, S=4, B=2, E=3200000
#define NN 100000
#define FF 128
#define OO 128
#define SS 4
#define BBASES 2
#define EE 3200000
#define TOTE (SS * EE)               // 12.8M edges total
#define RR 16                        // dest rows per bin (N % 16 == 0)
#define RSHIFT 4
#define NBINS ((NN + RR - 1) / RR)   // 6250
#define RBLOCKS 512                  // blocks for hist/reorder
#define SORTCAP 2560                 // max records sortable per bin (λ=2048, +11σ)

// clang vector types usable with __builtin_nontemporal_* (HIP uint2/float4 are not)
typedef unsigned int uintx2 __attribute__((ext_vector_type(2)));
typedef float floatx4 __attribute__((ext_vector_type(4)));

// ===========================================================================
// out[n] = tanh( g0[n] @ W0 + g1[n] @ W1 ),
//   g_b[n] = sum_s Wc[s,b] * sum_{e in s: row_e=n} val_e * feat[col_e]
// Pipeline: bin by row>>4 -> per-bin counting sort by row&15 (ballot-rank,
// no atomics) -> fused kernel: per-wave REGISTER accumulation over contiguous
// per-row edge runs (32-deep gather batches, sched_barrier-pinned), rare LDS
// flush on row change, then 16x128x(2x128) GEMM + tanh epilogue.
// ===========================================================================

__global__ __launch_bounds__(256) void hist_kernel(const int* __restrict__ rows,
                                                   unsigned int* __restrict__ hist) {
  __shared__ unsigned int lh[NBINS];
  for (int i = threadIdx.x; i < NBINS; i += 256) lh[i] = 0;
  __syncthreads();
  const int stride = gridDim.x * 256;
  for (int i = blockIdx.x * 256 + threadIdx.x; i < TOTE; i += stride)
    atomicAdd(&lh[((unsigned)rows[i]) >> RSHIFT], 1u);
  __syncthreads();
  for (int i = threadIdx.x; i < NBINS; i += 256) {
    unsigned int c = lh[i];
    if (c) atomicAdd(&hist[i], c);
  }
}

__global__ __launch_bounds__(256) void scan_kernel(const unsigned int* __restrict__ hist,
                                                   unsigned int* __restrict__ bin_start,
                                                   unsigned int* __restrict__ cursor) {
  __shared__ unsigned int sums[256];
  const int C = (NBINS + 255) / 256;  // 25
  const int t = threadIdx.x;
  unsigned int s = 0;
  for (int j = 0; j < C; ++j) {
    int i = t * C + j;
    if (i < NBINS) s += hist[i];
  }
  sums[t] = s;
  __syncthreads();
  for (int off = 1; off < 256; off <<= 1) {
    unsigned int v = (t >= off) ? sums[t - off] : 0u;
    __syncthreads();
    sums[t] += v;
    __syncthreads();
  }
  unsigned int base = (t == 0) ? 0u : sums[t - 1];
  for (int j = 0; j < C; ++j) {
    int i = t * C + j;
    if (i < NBINS) {
      unsigned int h = hist[i];
      bin_start[i] = base;
      cursor[i] = base;
      base += h;
    }
  }
  if (t == 255) bin_start[NBINS] = base;  // == TOTE
}

__global__ __launch_bounds__(256) void reorder_kernel(
    const int* __restrict__ rows, const int* __restrict__ cols,
    const float* __restrict__ vals, unsigned int* __restrict__ cursor,
    uintx2* __restrict__ sorted) {
  __shared__ unsigned int lcnt[NBINS];
  __shared__ unsigned int lbase[NBINS];
  const int C = (TOTE + RBLOCKS - 1) / RBLOCKS;  // 25000
  const int start = blockIdx.x * C;
  const int end = min(start + C, TOTE);
  for (int i = threadIdx.x; i < NBINS; i += 256) lcnt[i] = 0;
  __syncthreads();
  for (int i = start + threadIdx.x; i < end; i += 256)
    atomicAdd(&lcnt[((unsigned)rows[i]) >> RSHIFT], 1u);
  __syncthreads();
  for (int i = threadIdx.x; i < NBINS; i += 256) {
    unsigned int c = lcnt[i];
    if (c) lbase[i] = atomicAdd(&cursor[i], c);
    lcnt[i] = 0;
  }
  __syncthreads();
  for (int i = start + threadIdx.x; i < end; i += 256) {
    unsigned int r = (unsigned)rows[i];
    int bin = r >> RSHIFT;
    unsigned int p = lbase[bin] + atomicAdd(&lcnt[bin], 1u);
    int s = i / EE;  // support id
    uintx2 rec;
    // bits [16:0]=col, [20:17]=row-in-bin, [22:21]=support
    rec.x = ((unsigned)cols[i]) | ((r & (RR - 1u)) << 17) | (((unsigned)s) << 21);
    rec.y = __float_as_uint(vals[i]);
    __builtin_nontemporal_store(rec, &sorted[p]);
  }
}

// ---- per-bin counting sort by ro (16 buckets), ballot-rank, no atomics ----
__global__ __launch_bounds__(256) void sortbin_kernel(
    const unsigned int* __restrict__ bin_start, uintx2* __restrict__ sorted) {
  __shared__ uintx2 recs[SORTCAP];       // 20 KB
  __shared__ unsigned int tcnt[4][16];
  __shared__ unsigned int tstart[4][16];
  const int bin = blockIdx.x;
  const unsigned int e0 = bin_start[bin];
  const int L = (int)(bin_start[bin + 1] - e0);
  if (L <= 0 || L > SORTCAP) return;  // empty or oversized: leave unsorted (still correct)
  const int tid = threadIdx.x;
  const int lane = tid & 63;
  const int w = tid >> 6;
  for (int i = tid; i < L; i += 256)
    recs[i] = __builtin_nontemporal_load(&sorted[e0 + i]);
  __syncthreads();

  const unsigned long long below = (lane == 63) ? 0x7FFFFFFFFFFFFFFFull
                                                : ((1ull << lane) - 1ull);
  unsigned int cnt[16];
#pragma unroll
  for (int b = 0; b < 16; ++b) cnt[b] = 0;
  const int ROUNDS = (SORTCAP + 255) / 256;  // 10
  for (int r = 0; r < ROUNDS; ++r) {
    int idx = r * 256 + w * 64 + lane;
    unsigned int ro = 16u;
    if (idx < L) ro = (recs[idx].x >> 17) & 15u;
#pragma unroll
    for (int b = 0; b < 16; ++b)
      cnt[b] += (unsigned)__popcll(__ballot(ro == (unsigned)b));
  }
  unsigned int myv = 0;
#pragma unroll
  for (int b = 0; b < 16; ++b) myv = (lane == b) ? cnt[b] : myv;
  if (lane < 16) tcnt[w][lane] = myv;
  __syncthreads();
  if (tid == 0) {
    unsigned int run = 0;
    for (int b = 0; b < 16; ++b)
      for (int ww = 0; ww < 4; ++ww) {
        tstart[ww][b] = run;
        run += tcnt[ww][b];
      }
  }
  __syncthreads();
  unsigned int sb[16];
  {
    unsigned int t = (lane < 16) ? tstart[w][lane] : 0u;
#pragma unroll
    for (int b = 0; b < 16; ++b)
      sb[b] = (unsigned)__builtin_amdgcn_readlane((int)t, b);
  }
  for (int r = 0; r < ROUNDS; ++r) {
    int idx = r * 256 + w * 64 + lane;
    unsigned int ro = 16u;
    uintx2 rec;
    if (idx < L) {
      rec = recs[idx];
      ro = (rec.x >> 17) & 15u;
    }
    unsigned int dest = 0;
#pragma unroll
    for (int b = 0; b < 16; ++b) {
      unsigned long long m = __ballot(ro == (unsigned)b);
      unsigned int rk = (unsigned)__popcll(m & below);
      dest = (ro == (unsigned)b) ? (sb[b] + rk) : dest;
      sb[b] += (unsigned)__popcll(m);
    }
    if (idx < L) sorted[e0 + dest] = rec;
  }
}

// ---- fused: register accumulation + rare LDS flush + GEMM + tanh ----------
// Lane l holds feature elements 2l, 2l+1. G slot map: elem 2h+p -> p*64+h.
__global__ __launch_bounds__(256, 4) void fused_kernel(
    const float* __restrict__ feat, const float* __restrict__ W,
    const float* __restrict__ Wc, const uintx2* __restrict__ sorted,
    const unsigned int* __restrict__ bin_start, float* __restrict__ out) {
  __shared__ float G[2 * RR * FF];  // 16 KB: G0 then G1, [16][128] each
  const int tid = threadIdx.x;
  const int lane = tid & 63;
  const int wid = tid >> 6;

  float4* gz = (float4*)G;
#pragma unroll
  for (int i = 0; i < (2 * RR * FF / 4) / 256; ++i)  // 4 iters
    gz[tid + i * 256] = make_float4(0.f, 0.f, 0.f, 0.f);

  const float c00 = Wc[0], c01 = Wc[1], c10 = Wc[2], c11 = Wc[3];
  const float c20 = Wc[4], c21 = Wc[5], c30 = Wc[6], c31 = Wc[7];
  __syncthreads();

  const int bin = blockIdx.x;
  const unsigned int e0 = bin_start[bin];
  const unsigned int e1 = bin_start[bin + 1];
  const int L = (int)(e1 - e0);
  const unsigned int chunk = (((unsigned)(L + 3) >> 2) + 15u) & ~15u;
  unsigned int e = e0 + (unsigned)wid * chunk;
  unsigned int ew = e + chunk;
  if (ew > e1) ew = e1;

  float2 ga = make_float2(0.f, 0.f), gb = make_float2(0.f, 0.f);
  int cur_ro = -1;

  auto flushg = [&]() {
    if (cur_ro >= 0) {
      int a = (cur_ro << 7) + lane;
      atomicAdd(&G[a], ga.x);
      atomicAdd(&G[a + 64], ga.y);
      atomicAdd(&G[RR * FF + a], gb.x);
      atomicAdd(&G[RR * FF + a + 64], gb.y);
      ga = make_float2(0.f, 0.f);
      gb = make_float2(0.f, 0.f);
    }
  };
  auto consume1 = [&](unsigned int rxs, unsigned int rys, float2 xv) {
    int ro = (int)((rxs >> 17) & 15u);
    if (ro != cur_ro) {
      flushg();
      cur_ro = ro;
    }
    float v = __uint_as_float(rys);
    unsigned int s = (rxs >> 21) & 3u;
    float w0 = (s == 0) ? c00 : (s == 1) ? c10 : (s == 2) ? c20 : c30;
    float w1 = (s == 0) ? c01 : (s == 1) ? c11 : (s == 2) ? c21 : c31;
    float v0 = v * w0, v1 = v * w1;
    ga.x += v0 * xv.x;
    ga.y += v0 * xv.y;
    gb.x += v1 * xv.x;
    gb.y += v1 * xv.y;
  };

  // main: 32 edges per iteration, two 16-batches, gathers pinned in flight
  while (e + 32 <= ew) {
    uintx2 RA = __builtin_nontemporal_load(&sorted[e + (lane & 15)]);
    uintx2 RB = __builtin_nontemporal_load(&sorted[e + 16 + (lane & 15)]);
    float2 xA[16], xB[16];
#pragma unroll
    for (int j = 0; j < 16; ++j) {
      unsigned int c = (unsigned)__builtin_amdgcn_readlane((int)RA.x, j) & 0x1FFFFu;
      xA[j] = *reinterpret_cast<const float2*>(&feat[(c << 7) + (lane << 1)]);
    }
#pragma unroll
    for (int j = 0; j < 16; ++j) {
      unsigned int c = (unsigned)__builtin_amdgcn_readlane((int)RB.x, j) & 0x1FFFFu;
      xB[j] = *reinterpret_cast<const float2*>(&feat[(c << 7) + (lane << 1)]);
    }
    __builtin_amdgcn_sched_barrier(0);  // pin: all 32 gathers issued before consume
#pragma unroll
    for (int j = 0; j < 16; ++j)
      consume1((unsigned)__builtin_amdgcn_readlane((int)RA.x, j),
               (unsigned)__builtin_amdgcn_readlane((int)RA.y, j), xA[j]);
#pragma unroll
    for (int j = 0; j < 16; ++j)
      consume1((unsigned)__builtin_amdgcn_readlane((int)RB.x, j),
               (unsigned)__builtin_amdgcn_readlane((int)RB.y, j), xB[j]);
    e += 32;
  }
  // one remaining 16-batch
  if (e + 16 <= ew) {
    uintx2 RA = __builtin_nontemporal_load(&sorted[e + (lane & 15)]);
    float2 xA[16];
#pragma unroll
    for (int j = 0; j < 16; ++j) {
      unsigned int c = (unsigned)__builtin_amdgcn_readlane((int)RA.x, j) & 0x1FFFFu;
      xA[j] = *reinterpret_cast<const float2*>(&feat[(c << 7) + (lane << 1)]);
    }
    __builtin_amdgcn_sched_barrier(0);
#pragma unroll
    for (int j = 0; j < 16; ++j)
      consume1((unsigned)__builtin_amdgcn_readlane((int)RA.x, j),
               (unsigned)__builtin_amdgcn_readlane((int)RA.y, j), xA[j]);
    e += 16;
  }
  // 4-deep tail
  while (e + 4 <= ew) {
    uintx2 R4 = __builtin_nontemporal_load(&sorted[e + (lane & 3)]);
    float2 x4[4];
#pragma unroll
    for (int j = 0; j < 4; ++j) {
      unsigned int c = (unsigned)__builtin_amdgcn_readlane((int)R4.x, j) & 0x1FFFFu;
      x4[j] = *reinterpret_cast<const float2*>(&feat[(c << 7) + (lane << 1)]);
    }
    __builtin_amdgcn_sched_barrier(0);
#pragma unroll
    for (int j = 0; j < 4; ++j)
      consume1((unsigned)__builtin_amdgcn_readlane((int)R4.x, j),
               (unsigned)__builtin_amdgcn_readlane((int)R4.y, j), x4[j]);
    e += 4;
  }
  // singles
  while (e < ew) {
    uintx2 R1 = sorted[e];
    unsigned int rxs = (unsigned)__builtin_amdgcn_readlane((int)R1.x, 0);
    unsigned int rys = (unsigned)__builtin_amdgcn_readlane((int)R1.y, 0);
    unsigned int c = rxs & 0x1FFFFu;
    float2 xv = *reinterpret_cast<const float2*>(&feat[(c << 7) + (lane << 1)]);
    consume1(rxs, rys, xv);
    ++e;
  }
  flushg();
  __syncthreads();

  // ---- epilogue: out[bin*16 + r][o] = tanh(G0[r]@W0 + G1[r]@W1) ----
  const int tx = tid & 31;  // output cols tx*4 .. tx*4+3
  const int ty = tid >> 5;  // 0..7 -> rows 2ty, 2ty+1
  float acc[2][4];
#pragma unroll
  for (int r = 0; r < 2; ++r)
#pragma unroll
    for (int c = 0; c < 4; ++c) acc[r][c] = 0.f;

  const float* W0 = W;
  const float* W1 = W + FF * OO;
#pragma unroll
  for (int p = 0; p < 2; ++p) {
    for (int h0 = 0; h0 < 64; h0 += 4) {
      float4 a0[2], a1[2];
#pragma unroll
      for (int r = 0; r < 2; ++r) {
        a0[r] = *reinterpret_cast<const float4*>(
            &G[((ty * 2 + r) << 7) + p * 64 + h0]);
        a1[r] = *reinterpret_cast<const float4*>(
            &G[RR * FF + ((ty * 2 + r) << 7) + p * 64 + h0]);
      }
#pragma unroll
      for (int i = 0; i < 4; ++i) {
        int k = 2 * (h0 + i) + p;
        float4 b0 = *reinterpret_cast<const float4*>(&W0[k * OO + tx * 4]);
        float4 b1 = *reinterpret_cast<const float4*>(&W1[k * OO + tx * 4]);
#pragma unroll
        for (int r = 0; r < 2; ++r) {
          float g0 = reinterpret_cast<const float*>(&a0[r])[i];
          float g1 = reinterpret_cast<const float*>(&a1[r])[i];
          acc[r][0] += g0 * b0.x + g1 * b1.x;
          acc[r][1] += g0 * b0.y + g1 * b1.y;
          acc[r][2] += g0 * b0.z + g1 * b1.z;
          acc[r][3] += g0 * b0.w + g1 * b1.w;
        }
      }
    }
  }
#pragma unroll
  for (int r = 0; r < 2; ++r) {
    int row = bin * RR + ty * 2 + r;  // N divisible by 16
    floatx4 o;
    o.x = tanhf(acc[r][0]);
    o.y = tanhf(acc[r][1]);
    o.z = tanhf(acc[r][2]);
    o.w = tanhf(acc[r][3]);
    __builtin_nontemporal_store(o, (floatx4*)&out[(size_t)row * OO + tx * 4]);
  }
}

// ===========================================================================
// FALLBACK PATH (round-1, proven): used only if ws_size is too small
// ===========================================================================
__global__ void compute_V_kernel(const float* __restrict__ W,
                                 const float* __restrict__ Wc,
                                 float* __restrict__ V) {
  int i = blockIdx.x * blockDim.x + threadIdx.x;
  int s = i >> 14;
  int fo = i & 16383;
  V[i] = Wc[s * BBASES + 0] * W[fo] + Wc[s * BBASES + 1] * W[16384 + fo];
}

__global__ __launch_bounds__(256) void scatter_kernel(
    const float* __restrict__ feat, const int* __restrict__ rows,
    const int* __restrict__ cols, const float* __restrict__ vals,
    float* __restrict__ agg) {
  int t = blockIdx.x * blockDim.x + threadIdx.x;
  int e = t >> 5;
  int q = t & 31;
  if (e >= EE) return;
  int r = rows[e];
  int c = cols[e];
  float v = vals[e];
  const float4 x = *reinterpret_cast<const float4*>(&feat[(size_t)c * FF + q * 4]);
  float* dst = &agg[(size_t)r * FF + q * 4];
  unsafeAtomicAdd(dst + 0, v * x.x);
  unsafeAtomicAdd(dst + 1, v * x.y);
  unsafeAtomicAdd(dst + 2, v * x.z);
  unsafeAtomicAdd(dst + 3, v * x.w);
}

__global__ __launch_bounds__(256) void gemm_acc_kernel(
    const float* __restrict__ A, const float* __restrict__ Bv,
    float* __restrict__ C) {
  __shared__ float As[16][64];
  __shared__ float Bs[16][128];
  const int tid = threadIdx.x;
  const int bm0 = blockIdx.x * 64;
  const int tx = tid & 31;
  const int ty = tid >> 5;
  float acc[8][4];
#pragma unroll
  for (int r = 0; r < 8; ++r)
#pragma unroll
    for (int c = 0; c < 4; ++c) acc[r][c] = 0.0f;
  const int ar = tid >> 2;
  const int akq = tid & 3;
  for (int k0 = 0; k0 < FF; k0 += 16) {
    {
      int row = bm0 + ar;
      float4 av = make_float4(0.f, 0.f, 0.f, 0.f);
      if (row < NN)
        av = *reinterpret_cast<const float4*>(&A[(size_t)row * FF + k0 + akq * 4]);
      As[akq * 4 + 0][ar] = av.x;
      As[akq * 4 + 1][ar] = av.y;
      As[akq * 4 + 2][ar] = av.z;
      As[akq * 4 + 3][ar] = av.w;
    }
#pragma unroll
    for (int i = 0; i < 2; ++i) {
      int v = tid + i * 256;
      int kk = v >> 5;
      int cq = v & 31;
      *reinterpret_cast<float4*>(&Bs[kk][cq * 4]) =
          *reinterpret_cast<const float4*>(&Bv[(k0 + kk) * OO + cq * 4]);
    }
    __syncthreads();
#pragma unroll
    for (int kk = 0; kk < 16; ++kk) {
      float4 b = *reinterpret_cast<const float4*>(&Bs[kk][tx * 4]);
#pragma unroll
      for (int r = 0; r < 8; ++r) {
        float a = As[kk][ty * 8 + r];
        acc[r][0] += a * b.x;
        acc[r][1] += a * b.y;
        acc[r][2] += a * b.z;
        acc[r][3] += a * b.w;
      }
    }
    __syncthreads();
  }
#pragma unroll
  for (int r = 0; r < 8; ++r) {
    int row = bm0 + ty * 8 + r;
    if (row < NN) {
      float4* cp = reinterpret_cast<float4*>(&C[(size_t)row * OO + tx * 4]);
      float4 c = *cp;
      c.x += acc[r][0];
      c.y += acc[r][1];
      c.z += acc[r][2];
      c.w += acc[r][3];
      *cp = c;
    }
  }
}

__global__ __launch_bounds__(256) void tanh_kernel(float* __restrict__ out) {
  int i = blockIdx.x * blockDim.x + threadIdx.x;
  float4* p = reinterpret_cast<float4*>(out) + i;
  float4 v = *p;
  v.x = tanhf(v.x);
  v.y = tanhf(v.y);
  v.z = tanhf(v.z);
  v.w = tanhf(v.w);
  *p = v;
}

// ===========================================================================
extern "C" void kernel_launch(void* const* d_in, const int* in_sizes, int n_in,
                              void* d_out, int out_size, void* d_ws,
                              size_t ws_size, hipStream_t stream) {
  const float* feat = (const float*)d_in[0];   // [N, F]
  const float* W = (const float*)d_in[1];      // [B, F, O]
  const float* Wc = (const float*)d_in[2];     // [S, B]
  const int* erows = (const int*)d_in[3];      // [S, E]
  const int* ecols = (const int*)d_in[4];      // [S, E]
  const float* evals = (const float*)d_in[5];  // [S, E]
  float* out = (float*)d_out;                  // [N, O] f32

  unsigned char* ws = (unsigned char*)d_ws;
  unsigned int* hist = (unsigned int*)ws;                 // NBINS
  unsigned int* bin_start = hist + NBINS;                 // NBINS+1
  unsigned int* cursor = bin_start + NBINS + 1;           // NBINS
  size_t sorted_off = (((size_t)(3 * NBINS + 1) * 4) + 255) & ~(size_t)255;
  uintx2* sorted = (uintx2*)(ws + sorted_off);            // TOTE * 8B
  size_t needed = sorted_off + (size_t)TOTE * 8;

  if (ws_size >= needed) {
    hipMemsetAsync(hist, 0, (size_t)NBINS * 4, stream);
    hist_kernel<<<RBLOCKS, 256, 0, stream>>>(erows, hist);
    scan_kernel<<<1, 256, 0, stream>>>(hist, bin_start, cursor);
    reorder_kernel<<<RBLOCKS, 256, 0, stream>>>(erows, ecols, evals, cursor, sorted);
    sortbin_kernel<<<NBINS, 256, 0, stream>>>(bin_start, sorted);
    fused_kernel<<<NBINS, 256, 0, stream>>>(feat, W, Wc, sorted, bin_start, out);
  } else {
    float* V = (float*)d_ws;
    float* agg = V + (size_t)SS * FF * OO;
    compute_V_kernel<<<(SS * FF * OO) / 256, 256, 0, stream>>>(W, Wc, V);
    hipMemsetAsync(out, 0, (size_t)NN * OO * sizeof(float), stream);
    for (int s = 0; s < SS; ++s) {
      hipMemsetAsync(agg, 0, (size_t)NN * FF * sizeof(float), stream);
      scatter_kernel<<<(EE * 32) / 256, 256, 0, stream>>>(
          feat, erows + (size_t)s * EE, ecols + (size_t)s * EE,
          evals + (size_t)s * EE, agg);
      gemm_acc_kernel<<<(NN + 63) / 64, 256, 0, stream>>>(
          agg, V + (size_t)s * FF * OO, out);
    }
    tanh_kernel<<<(NN * OO / 4) / 256, 256, 0, stream>>>(out);
  }
}